// Round 1
// baseline (2611.497 us; speedup 1.0000x reference)
//
#include <hip/hip_runtime.h>
#include <hip/hip_bf16.h>
#include <math.h>

#define H_HEADS 16
#define SEQ 2048
#define DM 1024

// ---------------- Tiled fp32 GEMM: C = A(MxK) @ B(KxN) (+bias) ----------------
__global__ __launch_bounds__(256) void gemm_kernel(
    const float* __restrict__ A, const float* __restrict__ B,
    const float* __restrict__ bias, float* __restrict__ C,
    int M, int K, int N)
{
  __shared__ float As[16][65];   // As[k][m]
  __shared__ float Bs[16][65];   // Bs[k][n]
  const int n0 = blockIdx.x * 64, m0 = blockIdx.y * 64;
  const int tid = threadIdx.x;
  const int tx = tid & 15, ty = tid >> 4;
  float acc[4][4] = {};
  for (int kk = 0; kk < K; kk += 16) {
    {
      const int m = tid >> 2;
      const int kb = (tid & 3) * 4;
#pragma unroll
      for (int u = 0; u < 4; ++u) {
        const int k = kb + u;
        As[k][m] = (kk + k < K) ? A[(long)(m0 + m) * K + kk + k] : 0.0f;
      }
#pragma unroll
      for (int u = 0; u < 4; ++u) {
        const int idx = tid + 256 * u;
        const int k = idx >> 6, c = idx & 63;
        Bs[k][c] = (kk + k < K && n0 + c < N) ? B[(long)(kk + k) * N + n0 + c] : 0.0f;
      }
    }
    __syncthreads();
#pragma unroll
    for (int k = 0; k < 16; ++k) {
      float a[4], bb[4];
#pragma unroll
      for (int i = 0; i < 4; ++i) a[i] = As[k][ty * 4 + i];
#pragma unroll
      for (int j = 0; j < 4; ++j) bb[j] = Bs[k][tx * 4 + j];
#pragma unroll
      for (int i = 0; i < 4; ++i)
#pragma unroll
        for (int j = 0; j < 4; ++j) acc[i][j] += a[i] * bb[j];
    }
    __syncthreads();
  }
#pragma unroll
  for (int i = 0; i < 4; ++i) {
    const int m = m0 + ty * 4 + i;
#pragma unroll
    for (int j = 0; j < 4; ++j) {
      const int n = n0 + tx * 4 + j;
      if (n < N) C[(long)m * N + n] = acc[i][j] + (bias ? bias[n] : 0.0f);
    }
  }
}

// ---------------- Row-wise LayerNorm, in place. grid = rows, block = 256 ----------------
__global__ __launch_bounds__(256) void ln_kernel(
    float* __restrict__ X, const float* __restrict__ g, const float* __restrict__ b, int C)
{
  const int row = blockIdx.x, tid = threadIdx.x;
  float v = (tid < C) ? X[(long)row * C + tid] : 0.0f;
  float s1 = v, s2 = v * v;
#pragma unroll
  for (int off = 1; off < 64; off <<= 1) {
    s1 += __shfl_xor(s1, off);
    s2 += __shfl_xor(s2, off);
  }
  __shared__ float rA[4], rB[4];
  const int wid = tid >> 6;
  if ((tid & 63) == 0) { rA[wid] = s1; rB[wid] = s2; }
  __syncthreads();
  s1 = rA[0] + rA[1] + rA[2] + rA[3];
  s2 = rB[0] + rB[1] + rB[2] + rB[3];
  const float mean = s1 / C;
  const float var  = s2 / C - mean * mean;
  const float r = rsqrtf(var + 1e-5f);
  if (tid < C) X[(long)row * C + tid] = (v - mean) * r * g[tid] + b[tid];
}

// freq_i = 10000^(-i/16) = 2^(-i * log2(10000)/16)
__device__ __forceinline__ void rope_cs(int pos, int i, float& c, float& s) {
  const float freq = exp2f(-(float)i * 0.8304820237f);
  const float ang = (float)pos * freq;
  c = cosf(ang);
  s = sinf(ang);
}

// RoPE on q_rope (4096 rows x 512), in place. grid = 4096, block = 512.
__global__ __launch_bounds__(512) void rope_q_kernel(float* __restrict__ qr)
{
  const int row = blockIdx.x;
  const int e = threadIdx.x;            // 0..511 ; col = h*32 + d
  const int t = row & (SEQ - 1);
  const int d = e & 31, i = d >> 1;
  float c, s; rope_cs(t, i, c, s);
  const float v = qr[(long)row * 512 + e];
  const float p = __shfl_xor(v, 1);     // pair partner (d^1), same wave
  const float o = ((d & 1) == 0) ? (v * c - p * s)   // even: ev*cos - od*sin
                                 : (p * s + v * c);  // odd:  ev*sin + od*cos
  qr[(long)row * 512 + e] = o;
}

// RoPE on k_rope (4096 rows x 32), in place, includes /H. 131072 elems.
__global__ __launch_bounds__(256) void rope_kr_kernel(float* __restrict__ kr)
{
  const int idx = blockIdx.x * 256 + threadIdx.x;
  const int row = idx >> 5;
  const int d = idx & 31, i = d >> 1;
  const int spos = row & (SEQ - 1);
  float c, s; rope_cs(spos, i, c, s);
  const float v = kr[idx];
  const float p = __shfl_xor(v, 1);
  float o = ((d & 1) == 0) ? (v * c - p * s) : (p * s + v * c);
  kr[idx] = o * (1.0f / 16.0f);         // / H
}

// ---------------- Flash attention, fp32. grid = (B*H, T/64), block = 256 ----------------
// q = [qn | roped qr] (per row 512 = h*32+d), k = [kn | kr/H], v from vr (row*1024 + h*64 + d)
__global__ __launch_bounds__(256) void attn_kernel(
    const float* __restrict__ qn, const float* __restrict__ qr,
    const float* __restrict__ kn, const float* __restrict__ kr,
    const float* __restrict__ vr, float* __restrict__ o_buf)
{
  __shared__ float qs[64][65];
  __shared__ float ks[64][65];
  __shared__ float vs[64][65];
  const int bh = blockIdx.x;
  const int b = bh >> 4, h = bh & 15;
  const int t0 = blockIdx.y * 64;
  const int tid = threadIdx.x;
  const int tx = tid & 15, ty = tid >> 4;

  // load Q tile (scale 1/sqrt(64) folded in)
  for (int idx = tid; idx < 64 * 64; idx += 256) {
    const int r = idx >> 6, c = idx & 63;
    const long row = (long)b * SEQ + t0 + r;
    const float v = (c < 32) ? qn[row * 512 + h * 32 + c]
                             : qr[row * 512 + h * 32 + (c - 32)];
    qs[r][c] = v * 0.125f;
  }

  float acc[4][4] = {};
  float m_i[4], l_i[4];
#pragma unroll
  for (int i = 0; i < 4; ++i) { m_i[i] = -1e30f; l_i[i] = 0.0f; }

  for (int s0 = 0; s0 < SEQ; s0 += 64) {
    __syncthreads();   // protect ks/vs reuse
    for (int idx = tid; idx < 64 * 64; idx += 256) {
      const int r = idx >> 6, c = idx & 63;
      const long row = (long)b * SEQ + s0 + r;
      ks[r][c] = (c < 32) ? kn[row * 512 + h * 32 + c] : kr[row * 32 + (c - 32)];
      vs[r][c] = vr[row * 1024 + h * 64 + c];
    }
    __syncthreads();

    // scores 4x4: rows ty*4+i, cols tx*4+j
    float sc[4][4] = {};
#pragma unroll 8
    for (int d = 0; d < 64; ++d) {
      float a[4], bb[4];
#pragma unroll
      for (int i = 0; i < 4; ++i) a[i] = qs[ty * 4 + i][d];
#pragma unroll
      for (int j = 0; j < 4; ++j) bb[j] = ks[tx * 4 + j][d];
#pragma unroll
      for (int i = 0; i < 4; ++i)
#pragma unroll
        for (int j = 0; j < 4; ++j) sc[i][j] += a[i] * bb[j];
    }

    // online softmax per row (reduce across tx = 16 lanes within wave)
    float p[4][4];
#pragma unroll
    for (int i = 0; i < 4; ++i) {
      float mt = sc[i][0];
#pragma unroll
      for (int j = 1; j < 4; ++j) mt = fmaxf(mt, sc[i][j]);
#pragma unroll
      for (int off = 1; off < 16; off <<= 1) mt = fmaxf(mt, __shfl_xor(mt, off));
      const float mn = fmaxf(m_i[i], mt);
      const float al = __expf(m_i[i] - mn);
      m_i[i] = mn;
      float rs = 0.0f;
#pragma unroll
      for (int j = 0; j < 4; ++j) { p[i][j] = __expf(sc[i][j] - mn); rs += p[i][j]; }
#pragma unroll
      for (int off = 1; off < 16; off <<= 1) rs += __shfl_xor(rs, off);
      l_i[i] = l_i[i] * al + rs;
#pragma unroll
      for (int j = 0; j < 4; ++j) acc[i][j] *= al;
    }

    // acc += P @ V ; P row-block lives across the 16 tx lanes of this ty group
    const int laneBase = tid & 48;  // (lane>>4)<<4 within wave
#pragma unroll
    for (int cb = 0; cb < 16; ++cb) {
      float pv[4][4];
      const int src = laneBase | cb;
#pragma unroll
      for (int i = 0; i < 4; ++i)
#pragma unroll
        for (int j = 0; j < 4; ++j) pv[i][j] = __shfl(p[i][j], src);
#pragma unroll
      for (int jj = 0; jj < 4; ++jj) {
        const int c = cb * 4 + jj;
        float vv[4];
#pragma unroll
        for (int j = 0; j < 4; ++j) vv[j] = vs[c][tx * 4 + j];
#pragma unroll
        for (int i = 0; i < 4; ++i)
#pragma unroll
          for (int j = 0; j < 4; ++j) acc[i][j] += pv[i][jj] * vv[j];
      }
    }
  }

  // write O: o_buf[(b*T + t)*1024 + h*64 + dd]
#pragma unroll
  for (int i = 0; i < 4; ++i) {
    const float inv = 1.0f / l_i[i];
    const long t = t0 + ty * 4 + i;
    const long base = ((long)b * SEQ + t) * 1024 + h * 64 + tx * 4;
#pragma unroll
    for (int j = 0; j < 4; ++j) o_buf[base + j] = acc[i][j] * inv;
  }
}

extern "C" void kernel_launch(void* const* d_in, const int* in_sizes, int n_in,
                              void* d_out, int out_size, void* d_ws, size_t ws_size,
                              hipStream_t stream) {
  const float* x       = (const float*)d_in[0];
  const float* xf      = (const float*)d_in[1];
  const float* Wqc     = (const float*)d_in[2];
  const float* gq      = (const float*)d_in[3];
  const float* bq      = (const float*)d_in[4];
  const float* Wq_rope = (const float*)d_in[5];   // NOTE: rope before nope in dict order
  const float* Wq_nope = (const float*)d_in[6];
  const float* Wkvc    = (const float*)d_in[7];
  const float* gkv     = (const float*)d_in[8];
  const float* bkv     = (const float*)d_in[9];
  const float* Wk_nope = (const float*)d_in[10];
  const float* Wv      = (const float*)d_in[11];
  const float* Wkr     = (const float*)d_in[12];
  const float* Wo      = (const float*)d_in[13];
  const float* bo      = (const float*)d_in[14];
  float* out = (float*)d_out;

  float* ws = (float*)d_ws;
  const long R = 4096;                 // B*T = B*S
  float* ql    = ws;                   // 4096 x 256
  float* kvl   = ql    + R * 256;      // 4096 x 204
  float* kr    = kvl   + R * 204;      // 4096 x 32
  float* qn    = kr    + R * 32;       // 4096 x 512
  float* qr    = qn    + R * 512;      // 4096 x 512
  float* kn    = qr    + R * 512;      // 4096 x 512
  float* vrw   = kn    + R * 512;      // 4096 x 1024
  float* o_buf = vrw   + R * 1024;     // 4096 x 1024

  // 1) ql = LN(x @ Wqc)
  gemm_kernel<<<dim3(4, 64), 256, 0, stream>>>(x, Wqc, nullptr, ql, 4096, 1024, 256);
  ln_kernel<<<4096, 256, 0, stream>>>(ql, gq, bq, 256);
  // 2) kvl = LN(xf @ Wkvc)
  gemm_kernel<<<dim3(4, 64), 256, 0, stream>>>(xf, Wkvc, nullptr, kvl, 4096, 1024, 204);
  ln_kernel<<<4096, 256, 0, stream>>>(kvl, gkv, bkv, 204);
  // 3) kr = rope(xf @ Wkr) / H
  gemm_kernel<<<dim3(1, 64), 256, 0, stream>>>(xf, Wkr, nullptr, kr, 4096, 1024, 32);
  rope_kr_kernel<<<512, 256, 0, stream>>>(kr);
  // 4) q projections (+rope on rope part)
  gemm_kernel<<<dim3(8, 64), 256, 0, stream>>>(ql, Wq_nope, nullptr, qn, 4096, 256, 512);
  gemm_kernel<<<dim3(8, 64), 256, 0, stream>>>(ql, Wq_rope, nullptr, qr, 4096, 256, 512);
  rope_q_kernel<<<4096, 512, 0, stream>>>(qr);
  // 5) k_nope, v projections
  gemm_kernel<<<dim3(8, 64), 256, 0, stream>>>(kvl, Wk_nope, nullptr, kn, 4096, 204, 512);
  gemm_kernel<<<dim3(16, 64), 256, 0, stream>>>(kvl, Wv, nullptr, vrw, 4096, 204, 1024);
  // 6) attention -> o_buf (B,T,H*64)
  attn_kernel<<<dim3(32, 32), 256, 0, stream>>>(qn, qr, kn, kr, vrw, o_buf);
  // 7) out = o_buf @ Wo + bo
  gemm_kernel<<<dim3(16, 64), 256, 0, stream>>>(o_buf, Wo, bo, out, 4096, 1024, 1024);
}

// Round 2
// 1133.609 us; speedup vs baseline: 2.3037x; 2.3037x over previous
//
#include <hip/hip_runtime.h>
#include <hip/hip_bf16.h>
#include <math.h>

#define SEQ 2048

typedef __bf16 bf16x8 __attribute__((ext_vector_type(8)));
typedef float  f32x4  __attribute__((ext_vector_type(4)));

__device__ __forceinline__ unsigned short f2bf(float f) {
  __bf16 h = (__bf16)f;
  return __builtin_bit_cast(unsigned short, h);
}

__device__ __forceinline__ void store_out(float* C, long idx, float v) { C[idx] = v; }
__device__ __forceinline__ void store_out(unsigned short* C, long idx, float v) { C[idx] = f2bf(v); }

// ---------------- Tiled fp32 GEMM: C = A(MxK) @ B(KxN) (+bias), OT output ----------------
template <typename OT>
__global__ __launch_bounds__(256) void gemm_kernel(
    const float* __restrict__ A, const float* __restrict__ B,
    const float* __restrict__ bias, OT* __restrict__ C,
    int M, int K, int N)
{
  __shared__ float As[16][65];   // As[k][m]
  __shared__ float Bs[16][65];   // Bs[k][n]
  const int n0 = blockIdx.x * 64, m0 = blockIdx.y * 64;
  const int tid = threadIdx.x;
  const int tx = tid & 15, ty = tid >> 4;
  float acc[4][4] = {};
  for (int kk = 0; kk < K; kk += 16) {
    {
      const int m = tid >> 2;
      const int kb = (tid & 3) * 4;
#pragma unroll
      for (int u = 0; u < 4; ++u) {
        const int k = kb + u;
        As[k][m] = (kk + k < K) ? A[(long)(m0 + m) * K + kk + k] : 0.0f;
      }
#pragma unroll
      for (int u = 0; u < 4; ++u) {
        const int idx = tid + 256 * u;
        const int k = idx >> 6, c = idx & 63;
        Bs[k][c] = (kk + k < K && n0 + c < N) ? B[(long)(kk + k) * N + n0 + c] : 0.0f;
      }
    }
    __syncthreads();
#pragma unroll
    for (int k = 0; k < 16; ++k) {
      float a[4], bb[4];
#pragma unroll
      for (int i = 0; i < 4; ++i) a[i] = As[k][ty * 4 + i];
#pragma unroll
      for (int j = 0; j < 4; ++j) bb[j] = Bs[k][tx * 4 + j];
#pragma unroll
      for (int i = 0; i < 4; ++i)
#pragma unroll
        for (int j = 0; j < 4; ++j) acc[i][j] += a[i] * bb[j];
    }
    __syncthreads();
  }
#pragma unroll
  for (int i = 0; i < 4; ++i) {
    const int m = m0 + ty * 4 + i;
#pragma unroll
    for (int j = 0; j < 4; ++j) {
      const int n = n0 + tx * 4 + j;
      if (n < N) store_out(C, (long)m * N + n, acc[i][j] + (bias ? bias[n] : 0.0f));
    }
  }
}

// ---------------- Row-wise LayerNorm, in place. grid = rows, block = 256 ----------------
__global__ __launch_bounds__(256) void ln_kernel(
    float* __restrict__ X, const float* __restrict__ g, const float* __restrict__ b, int C)
{
  const int row = blockIdx.x, tid = threadIdx.x;
  float v = (tid < C) ? X[(long)row * C + tid] : 0.0f;
  float s1 = v, s2 = v * v;
#pragma unroll
  for (int off = 1; off < 64; off <<= 1) {
    s1 += __shfl_xor(s1, off);
    s2 += __shfl_xor(s2, off);
  }
  __shared__ float rA[4], rB[4];
  const int wid = tid >> 6;
  if ((tid & 63) == 0) { rA[wid] = s1; rB[wid] = s2; }
  __syncthreads();
  s1 = rA[0] + rA[1] + rA[2] + rA[3];
  s2 = rB[0] + rB[1] + rB[2] + rB[3];
  const float mean = s1 / C;
  const float var  = s2 / C - mean * mean;
  const float r = rsqrtf(var + 1e-5f);
  if (tid < C) X[(long)row * C + tid] = (v - mean) * r * g[tid] + b[tid];
}

// freq_i = 10000^(-i/16) = 2^(-i * log2(10000)/16)
__device__ __forceinline__ void rope_cs(int pos, int i, float& c, float& s) {
  const float freq = exp2f(-(float)i * 0.8304820237f);
  const float ang = (float)pos * freq;
  c = cosf(ang);
  s = sinf(ang);
}

// RoPE on q_rope (4096 rows x 512) fp32 -> bf16. grid = 4096, block = 512.
__global__ __launch_bounds__(512) void rope_q_kernel(
    const float* __restrict__ qf, unsigned short* __restrict__ qb)
{
  const int row = blockIdx.x;
  const int e = threadIdx.x;            // col = h*32 + d
  const int t = row & (SEQ - 1);
  const int d = e & 31, i = d >> 1;
  float c, s; rope_cs(t, i, c, s);
  const float v = qf[(long)row * 512 + e];
  const float p = __shfl_xor(v, 1);     // pair partner (d^1), same wave
  const float o = ((d & 1) == 0) ? (v * c - p * s) : (p * s + v * c);
  qb[(long)row * 512 + e] = f2bf(o);
}

// RoPE on k_rope (4096 rows x 32) fp32 -> bf16, includes /H.
__global__ __launch_bounds__(256) void rope_kr_kernel(
    const float* __restrict__ kf, unsigned short* __restrict__ kb)
{
  const int idx = blockIdx.x * 256 + threadIdx.x;
  const int row = idx >> 5;
  const int d = idx & 31, i = d >> 1;
  const int spos = row & (SEQ - 1);
  float c, s; rope_cs(spos, i, c, s);
  const float v = kf[idx];
  const float p = __shfl_xor(v, 1);
  float o = ((d & 1) == 0) ? (v * c - p * s) : (p * s + v * c);
  kb[idx] = f2bf(o * (1.0f / 16.0f));
}

// ---------------- V transpose + cast: v_f (B,S,H,64) f32 -> vT (B,H,64,S) bf16 --------
// grid = (s-tiles=32, bh=32), block 256
__global__ __launch_bounds__(256) void transpose_v_kernel(
    const float* __restrict__ vf, unsigned short* __restrict__ vT)
{
  __shared__ float tile[64][65];
  const int bh = blockIdx.y;
  const int b = bh >> 4, h = bh & 15;
  const int s0 = blockIdx.x * 64;
  const int tid = threadIdx.x;
  for (int idx = tid; idx < 4096; idx += 256) {
    const int r = idx >> 6, c = idx & 63;     // r = s offset, c = d
    tile[r][c] = vf[((long)b * SEQ + s0 + r) * 1024 + h * 64 + c];
  }
  __syncthreads();
  for (int idx = tid; idx < 4096; idx += 256) {
    const int d = idx >> 6, si = idx & 63;
    vT[((long)bh * 64 + d) * SEQ + s0 + si] = f2bf(tile[si][d]);
  }
}

// ---------------- MFMA flash attention, bf16. grid = (t-tiles=32, bh=32), block 256 ----
// Q/K rows are [32 nope | 32 rope] (d=64). V transposed: vT[bh][d][s].
__global__ __launch_bounds__(256) void attn_mfma_kernel(
    const unsigned short* __restrict__ qn, const unsigned short* __restrict__ qr,
    const unsigned short* __restrict__ kn, const unsigned short* __restrict__ kr,
    const unsigned short* __restrict__ vT, float* __restrict__ o_buf)
{
  __shared__ unsigned short Qs[64 * 72];
  __shared__ unsigned short Ks[64 * 72];
  __shared__ unsigned short Vs[64 * 72];   // Vs[d][s]
  __shared__ unsigned short Ps[64 * 72];
  const int bh = blockIdx.y;
  const int b = bh >> 4, h = bh & 15;
  const int t0 = blockIdx.x * 64;
  const int tid = threadIdx.x;
  const int w = tid >> 6, lane = tid & 63;
  const int ln16 = lane & 15, quad = lane >> 4;
  const int mrow = w * 16;

  // stage Q (64 rows x 64 cols), 16B chunks
  for (int q = tid; q < 512; q += 256) {
    const int r = q >> 3, c8 = (q & 7) * 8;
    const long row = (long)b * SEQ + t0 + r;
    bf16x8 val = (c8 < 32) ? *(const bf16x8*)&qn[row * 512 + h * 32 + c8]
                           : *(const bf16x8*)&qr[row * 512 + h * 32 + (c8 - 32)];
    *(bf16x8*)&Qs[r * 72 + c8] = val;
  }

  f32x4 o_acc[4];
  float m_i[4], l_i[4];
#pragma unroll
  for (int i = 0; i < 4; ++i) {
    m_i[i] = -1e30f; l_i[i] = 0.0f;
#pragma unroll
    for (int k = 0; k < 4; ++k) o_acc[i][k] = 0.0f;
  }

  for (int s0 = 0; s0 < SEQ; s0 += 64) {
    __syncthreads();
    // stage K (rows=s, cols=d) and V^T (rows=d, cols=s)
    for (int q = tid; q < 512; q += 256) {
      const int r = q >> 3, c8 = (q & 7) * 8;
      const long row = (long)b * SEQ + s0 + r;
      bf16x8 kv = (c8 < 32) ? *(const bf16x8*)&kn[row * 512 + h * 32 + c8]
                            : *(const bf16x8*)&kr[row * 32 + (c8 - 32)];
      *(bf16x8*)&Ks[r * 72 + c8] = kv;
      bf16x8 vv = *(const bf16x8*)&vT[((long)bh * 64 + r) * SEQ + s0 + c8];
      *(bf16x8*)&Vs[r * 72 + c8] = vv;
    }
    __syncthreads();

    // S = Q(16x64) @ K^T(64x64) per wave -> 4 col-tiles
    f32x4 s_frag[4];
#pragma unroll
    for (int nt = 0; nt < 4; ++nt)
#pragma unroll
      for (int k = 0; k < 4; ++k) s_frag[nt][k] = 0.0f;
#pragma unroll
    for (int kk = 0; kk < 64; kk += 32) {
      bf16x8 a = *(const bf16x8*)&Qs[(mrow + ln16) * 72 + kk + quad * 8];
#pragma unroll
      for (int nt = 0; nt < 4; ++nt) {
        bf16x8 bb = *(const bf16x8*)&Ks[(nt * 16 + ln16) * 72 + kk + quad * 8];
        s_frag[nt] = __builtin_amdgcn_mfma_f32_16x16x32_bf16(a, bb, s_frag[nt], 0, 0, 0);
      }
    }

    // online softmax (rows = quad*4+reg, cols = nt*16 + ln16), scale 1/8
#pragma unroll
    for (int reg = 0; reg < 4; ++reg) {
      float mv = s_frag[0][reg] * 0.125f;
#pragma unroll
      for (int nt = 0; nt < 4; ++nt) {
        s_frag[nt][reg] *= 0.125f;
        mv = fmaxf(mv, s_frag[nt][reg]);
      }
#pragma unroll
      for (int off = 1; off < 16; off <<= 1) mv = fmaxf(mv, __shfl_xor(mv, off));
      const float mn = fmaxf(m_i[reg], mv);
      const float al = __expf(m_i[reg] - mn);
      m_i[reg] = mn;
      float rs = 0.0f;
#pragma unroll
      for (int nt = 0; nt < 4; ++nt) {
        const float p = __expf(s_frag[nt][reg] - mn);
        s_frag[nt][reg] = p;
        rs += p;
      }
#pragma unroll
      for (int off = 1; off < 16; off <<= 1) rs += __shfl_xor(rs, off);
      l_i[reg] = l_i[reg] * al + rs;
#pragma unroll
      for (int nt = 0; nt < 4; ++nt) o_acc[nt][reg] *= al;
    }

    // P -> LDS (wave-private 16 rows), bf16
#pragma unroll
    for (int nt = 0; nt < 4; ++nt)
#pragma unroll
      for (int reg = 0; reg < 4; ++reg)
        Ps[(mrow + quad * 4 + reg) * 72 + nt * 16 + ln16] = f2bf(s_frag[nt][reg]);

    // O += P(16x64) @ V(64x64)
#pragma unroll
    for (int kk = 0; kk < 64; kk += 32) {
      bf16x8 a = *(const bf16x8*)&Ps[(mrow + ln16) * 72 + kk + quad * 8];
#pragma unroll
      for (int nt = 0; nt < 4; ++nt) {
        bf16x8 bb = *(const bf16x8*)&Vs[(nt * 16 + ln16) * 72 + kk + quad * 8];
        o_acc[nt] = __builtin_amdgcn_mfma_f32_16x16x32_bf16(a, bb, o_acc[nt], 0, 0, 0);
      }
    }
  }

  // write O: o_buf[(b*T + t)*1024 + h*64 + col]
#pragma unroll
  for (int reg = 0; reg < 4; ++reg) {
    const float inv = 1.0f / l_i[reg];
    const long t = t0 + mrow + quad * 4 + reg;
    const long base = ((long)b * SEQ + t) * 1024 + h * 64 + ln16;
#pragma unroll
    for (int nt = 0; nt < 4; ++nt)
      o_buf[base + nt * 16] = o_acc[nt][reg] * inv;
  }
}

extern "C" void kernel_launch(void* const* d_in, const int* in_sizes, int n_in,
                              void* d_out, int out_size, void* d_ws, size_t ws_size,
                              hipStream_t stream) {
  const float* x       = (const float*)d_in[0];
  const float* xf      = (const float*)d_in[1];
  const float* Wqc     = (const float*)d_in[2];
  const float* gq      = (const float*)d_in[3];
  const float* bq      = (const float*)d_in[4];
  const float* Wq_rope = (const float*)d_in[5];   // rope before nope in dict order
  const float* Wq_nope = (const float*)d_in[6];
  const float* Wkvc    = (const float*)d_in[7];
  const float* gkv     = (const float*)d_in[8];
  const float* bkv     = (const float*)d_in[9];
  const float* Wk_nope = (const float*)d_in[10];
  const float* Wv      = (const float*)d_in[11];
  const float* Wkr     = (const float*)d_in[12];
  const float* Wo      = (const float*)d_in[13];
  const float* bo      = (const float*)d_in[14];
  float* out = (float*)d_out;

  const long R = 4096;
  float* ws = (float*)d_ws;
  float* ql      = ws;                    // 4096 x 256 f32
  float* kvl     = ql + R * 256;          // 4096 x 204 f32
  float* o_buf   = kvl + R * 204;         // 4096 x 1024 f32
  float* scratch = o_buf + R * 1024;      // 4096 x 1024 f32 (kr_f / qr_f / v_f, sequential)
  unsigned short* qn_bf = (unsigned short*)(scratch + R * 1024);  // 4096 x 512
  unsigned short* qr_bf = qn_bf + R * 512;                        // 4096 x 512
  unsigned short* kn_bf = qr_bf + R * 512;                        // 4096 x 512
  unsigned short* kr_bf = kn_bf + R * 512;                        // 4096 x 32
  unsigned short* vT_bf = kr_bf + R * 32;                         // 4096 x 1024 (B,H,64,S)

  // 1) ql = LN(x @ Wqc)
  gemm_kernel<float><<<dim3(4, 64), 256, 0, stream>>>(x, Wqc, nullptr, ql, 4096, 1024, 256);
  ln_kernel<<<4096, 256, 0, stream>>>(ql, gq, bq, 256);
  // 2) kvl = LN(xf @ Wkvc)
  gemm_kernel<float><<<dim3(4, 64), 256, 0, stream>>>(xf, Wkvc, nullptr, kvl, 4096, 1024, 204);
  ln_kernel<<<4096, 256, 0, stream>>>(kvl, gkv, bkv, 204);
  // 3) kr = rope(xf @ Wkr)/H -> bf16
  gemm_kernel<float><<<dim3(1, 64), 256, 0, stream>>>(xf, Wkr, nullptr, scratch, 4096, 1024, 32);
  rope_kr_kernel<<<512, 256, 0, stream>>>(scratch, kr_bf);
  // 4) qn = ql @ Wq_nope -> bf16
  gemm_kernel<unsigned short><<<dim3(8, 64), 256, 0, stream>>>(ql, Wq_nope, nullptr, qn_bf, 4096, 256, 512);
  // 5) qr = rope(ql @ Wq_rope) -> bf16
  gemm_kernel<float><<<dim3(8, 64), 256, 0, stream>>>(ql, Wq_rope, nullptr, scratch, 4096, 256, 512);
  rope_q_kernel<<<4096, 512, 0, stream>>>(scratch, qr_bf);
  // 6) kn = kvl @ Wk_nope -> bf16
  gemm_kernel<unsigned short><<<dim3(8, 64), 256, 0, stream>>>(kvl, Wk_nope, nullptr, kn_bf, 4096, 204, 512);
  // 7) v = kvl @ Wv -> f32, then transpose+cast to vT bf16
  gemm_kernel<float><<<dim3(16, 64), 256, 0, stream>>>(kvl, Wv, nullptr, scratch, 4096, 204, 1024);
  transpose_v_kernel<<<dim3(32, 32), 256, 0, stream>>>(scratch, vT_bf);
  // 8) attention -> o_buf (B,T,H*64) f32
  attn_mfma_kernel<<<dim3(32, 32), 256, 0, stream>>>(qn_bf, qr_bf, kn_bf, kr_bf, vT_bf, o_buf);
  // 9) out = o_buf @ Wo + bo
  gemm_kernel<float><<<dim3(16, 64), 256, 0, stream>>>(o_buf, Wo, bo, out, 4096, 1024, 1024);
}

// Round 3
// 416.562 us; speedup vs baseline: 6.2692x; 2.7213x over previous
//
#include <hip/hip_runtime.h>
#include <hip/hip_bf16.h>
#include <math.h>

#define SEQ 2048

typedef __bf16 bf16x8 __attribute__((ext_vector_type(8)));
typedef float  f32x4  __attribute__((ext_vector_type(4)));

__device__ __forceinline__ unsigned short f2bf(float f) {
  __bf16 h = (__bf16)f;
  return __builtin_bit_cast(unsigned short, h);
}

__device__ __forceinline__ void store_out(float* C, long idx, float v) { C[idx] = v; }
__device__ __forceinline__ void store_out(unsigned short* C, long idx, float v) { C[idx] = f2bf(v); }

__device__ __forceinline__ void gload16(const unsigned short* g, unsigned short* l) {
  __builtin_amdgcn_global_load_lds(
      (const __attribute__((address_space(1))) void*)g,
      (__attribute__((address_space(3))) void*)l, 16, 0, 0);
}

// ---------------- fp32 -> bf16 cast, 4 elems/thread ----------------
__global__ __launch_bounds__(256) void cast_kernel(
    const float* __restrict__ src, unsigned short* __restrict__ dst, int n)
{
  const int i = (blockIdx.x * 256 + threadIdx.x) * 4;
  if (i + 3 < n) {
    const float4 v = *(const float4*)&src[i];
    ushort4 o;
    o.x = f2bf(v.x); o.y = f2bf(v.y); o.z = f2bf(v.z); o.w = f2bf(v.w);
    *(ushort4*)&dst[i] = o;
  }
}

// ------------- transpose + cast: W (K x N fp32) -> WT (NR x KC bf16, zero-padded) -------
// grid = (KC/32, NR/32), block 256
__global__ __launch_bounds__(256) void transpose_cast_kernel(
    const float* __restrict__ src, unsigned short* __restrict__ dst,
    int K, int N, int NR, int KC)
{
  __shared__ float tile[32][33];
  const int k0 = blockIdx.x * 32, n0 = blockIdx.y * 32;
  const int tx = threadIdx.x & 31, ty = threadIdx.x >> 5;   // 32 x 8
  for (int r = ty; r < 32; r += 8) {
    const int k = k0 + r, n = n0 + tx;
    tile[r][tx] = (k < K && n < N) ? src[(long)k * N + n] : 0.0f;
  }
  __syncthreads();
  for (int r = ty; r < 32; r += 8) {
    const int n = n0 + r, k = k0 + tx;
    dst[(long)n * KC + k] = f2bf(tile[tx][r]);
  }
}

// ---------------- bf16 MFMA GEMM: C(MxN) = A(MxK) @ BT(NRxK)^T (+bias) ----------------
// K mult of 32; M mult of 128; BT has gridDim.x*128 zero-padded rows.
// grid = (ceil(N/128), M/128), block 256.
template <typename OT, bool BIAS>
__global__ __launch_bounds__(256) void gemm_mfma(
    const unsigned short* __restrict__ A, const unsigned short* __restrict__ BT,
    const float* __restrict__ bias, OT* __restrict__ C,
    int K, int N)
{
  __shared__ unsigned short As[128 * 32];
  __shared__ unsigned short Bs[128 * 32];
  const int tid = threadIdx.x;
  const int w = tid >> 6, lane = tid & 63;
  const int ln16 = lane & 15, quad = lane >> 4;
  const int wm = (w >> 1) * 64, wn = (w & 1) * 64;
  const int m0 = blockIdx.y * 128, n0 = blockIdx.x * 128;
  const int rr = tid >> 2, cc = (tid & 3) * 8;

  f32x4 acc[4][4];
#pragma unroll
  for (int i = 0; i < 4; ++i)
#pragma unroll
    for (int j = 0; j < 4; ++j)
#pragma unroll
      for (int r = 0; r < 4; ++r) acc[i][j][r] = 0.0f;

  for (int k0 = 0; k0 < K; k0 += 32) {
    __syncthreads();
    gload16(&A [(long)(m0 + rr)      * K + k0 + cc], &As[rr * 32 + cc]);
    gload16(&A [(long)(m0 + 64 + rr) * K + k0 + cc], &As[(64 + rr) * 32 + cc]);
    gload16(&BT[(long)(n0 + rr)      * K + k0 + cc], &Bs[rr * 32 + cc]);
    gload16(&BT[(long)(n0 + 64 + rr) * K + k0 + cc], &Bs[(64 + rr) * 32 + cc]);
    __syncthreads();
    bf16x8 fa[4], fb[4];
#pragma unroll
    for (int i = 0; i < 4; ++i) fa[i] = *(const bf16x8*)&As[(wm + i * 16 + ln16) * 32 + quad * 8];
#pragma unroll
    for (int j = 0; j < 4; ++j) fb[j] = *(const bf16x8*)&Bs[(wn + j * 16 + ln16) * 32 + quad * 8];
#pragma unroll
    for (int i = 0; i < 4; ++i)
#pragma unroll
      for (int j = 0; j < 4; ++j)
        acc[i][j] = __builtin_amdgcn_mfma_f32_16x16x32_bf16(fa[i], fb[j], acc[i][j], 0, 0, 0);
  }

#pragma unroll
  for (int i = 0; i < 4; ++i) {
    const int row = m0 + wm + i * 16 + quad * 4;
#pragma unroll
    for (int j = 0; j < 4; ++j) {
      const int col = n0 + wn + j * 16 + ln16;
      if (col < N) {
        float bv = 0.0f;
        if (BIAS) bv = bias[col];
#pragma unroll
        for (int r = 0; r < 4; ++r)
          store_out(C, (long)(row + r) * N + col, acc[i][j][r] + bv);
      }
    }
  }
}

// ------------- Row-wise LayerNorm fp32 -> bf16 (padded). grid = rows, block = 256 -------
__global__ __launch_bounds__(256) void ln_kernel(
    const float* __restrict__ X, const float* __restrict__ g, const float* __restrict__ b,
    unsigned short* __restrict__ Y, int C, int Cp)
{
  const int row = blockIdx.x, tid = threadIdx.x;
  float v = (tid < C) ? X[(long)row * C + tid] : 0.0f;
  float s1 = v, s2 = v * v;
#pragma unroll
  for (int off = 1; off < 64; off <<= 1) {
    s1 += __shfl_xor(s1, off);
    s2 += __shfl_xor(s2, off);
  }
  __shared__ float rA[4], rB[4];
  const int wid = tid >> 6;
  if ((tid & 63) == 0) { rA[wid] = s1; rB[wid] = s2; }
  __syncthreads();
  s1 = rA[0] + rA[1] + rA[2] + rA[3];
  s2 = rB[0] + rB[1] + rB[2] + rB[3];
  const float mean = s1 / C;
  const float var  = s2 / C - mean * mean;
  const float r = rsqrtf(var + 1e-5f);
  if (tid < C) Y[(long)row * Cp + tid] = f2bf((v - mean) * r * g[tid] + b[tid]);
  else if (tid < Cp) Y[(long)row * Cp + tid] = 0;
}

// freq_i = 10000^(-i/16) = 2^(-i * log2(10000)/16)
__device__ __forceinline__ void rope_cs(int pos, int i, float& c, float& s) {
  const float freq = exp2f(-(float)i * 0.8304820237f);
  const float ang = (float)pos * freq;
  c = cosf(ang);
  s = sinf(ang);
}

// RoPE on q_rope (4096 rows x 512) fp32 -> bf16. grid = 4096, block = 512.
__global__ __launch_bounds__(512) void rope_q_kernel(
    const float* __restrict__ qf, unsigned short* __restrict__ qb)
{
  const int row = blockIdx.x;
  const int e = threadIdx.x;            // col = h*32 + d
  const int t = row & (SEQ - 1);
  const int d = e & 31, i = d >> 1;
  float c, s; rope_cs(t, i, c, s);
  const float v = qf[(long)row * 512 + e];
  const float p = __shfl_xor(v, 1);
  const float o = ((d & 1) == 0) ? (v * c - p * s) : (p * s + v * c);
  qb[(long)row * 512 + e] = f2bf(o);
}

// RoPE on k_rope (4096 rows x 32) fp32 -> bf16, includes /H.
__global__ __launch_bounds__(256) void rope_kr_kernel(
    const float* __restrict__ kf, unsigned short* __restrict__ kb)
{
  const int idx = blockIdx.x * 256 + threadIdx.x;
  const int row = idx >> 5;
  const int d = idx & 31, i = d >> 1;
  const int spos = row & (SEQ - 1);
  float c, s; rope_cs(spos, i, c, s);
  const float v = kf[idx];
  const float p = __shfl_xor(v, 1);
  float o = ((d & 1) == 0) ? (v * c - p * s) : (p * s + v * c);
  kb[idx] = f2bf(o * (1.0f / 16.0f));
}

// ---------------- V transpose: v (B,S,H,64) bf16 -> vT (B,H,64,S) bf16 --------
// grid = (s-tiles=32, bh=32), block 256
__global__ __launch_bounds__(256) void transpose_v_kernel(
    const unsigned short* __restrict__ vf, unsigned short* __restrict__ vT)
{
  __shared__ unsigned short tile[64][72];
  const int bh = blockIdx.y;
  const int b = bh >> 4, h = bh & 15;
  const int s0 = blockIdx.x * 64;
  const int tid = threadIdx.x;
  for (int idx = tid; idx < 4096; idx += 256) {
    const int r = idx >> 6, c = idx & 63;     // r = s offset, c = d
    tile[r][c] = vf[((long)b * SEQ + s0 + r) * 1024 + h * 64 + c];
  }
  __syncthreads();
  for (int idx = tid; idx < 4096; idx += 256) {
    const int d = idx >> 6, si = idx & 63;
    vT[((long)bh * 64 + d) * SEQ + s0 + si] = tile[si][d];
  }
}

// ---------------- MFMA flash attention, bf16. grid = (t-tiles=32, bh=32), block 256 ----
__global__ __launch_bounds__(256) void attn_mfma_kernel(
    const unsigned short* __restrict__ qn, const unsigned short* __restrict__ qr,
    const unsigned short* __restrict__ kn, const unsigned short* __restrict__ kr,
    const unsigned short* __restrict__ vT, unsigned short* __restrict__ ob)
{
  __shared__ unsigned short Qs[64 * 72];
  __shared__ unsigned short Ks[64 * 72];
  __shared__ unsigned short Vs[64 * 72];   // Vs[d][s]
  __shared__ unsigned short Ps[64 * 72];
  const int bh = blockIdx.y;
  const int b = bh >> 4, h = bh & 15;
  const int t0 = blockIdx.x * 64;
  const int tid = threadIdx.x;
  const int w = tid >> 6, lane = tid & 63;
  const int ln16 = lane & 15, quad = lane >> 4;
  const int mrow = w * 16;

  for (int q = tid; q < 512; q += 256) {
    const int r = q >> 3, c8 = (q & 7) * 8;
    const long row = (long)b * SEQ + t0 + r;
    bf16x8 val = (c8 < 32) ? *(const bf16x8*)&qn[row * 512 + h * 32 + c8]
                           : *(const bf16x8*)&qr[row * 512 + h * 32 + (c8 - 32)];
    *(bf16x8*)&Qs[r * 72 + c8] = val;
  }

  f32x4 o_acc[4];
  float m_i[4], l_i[4];
#pragma unroll
  for (int i = 0; i < 4; ++i) {
    m_i[i] = -1e30f; l_i[i] = 0.0f;
#pragma unroll
    for (int k = 0; k < 4; ++k) o_acc[i][k] = 0.0f;
  }

  for (int s0 = 0; s0 < SEQ; s0 += 64) {
    __syncthreads();
    for (int q = tid; q < 512; q += 256) {
      const int r = q >> 3, c8 = (q & 7) * 8;
      const long row = (long)b * SEQ + s0 + r;
      bf16x8 kv = (c8 < 32) ? *(const bf16x8*)&kn[row * 512 + h * 32 + c8]
                            : *(const bf16x8*)&kr[row * 32 + (c8 - 32)];
      *(bf16x8*)&Ks[r * 72 + c8] = kv;
      bf16x8 vv = *(const bf16x8*)&vT[((long)bh * 64 + r) * SEQ + s0 + c8];
      *(bf16x8*)&Vs[r * 72 + c8] = vv;
    }
    __syncthreads();

    f32x4 s_frag[4];
#pragma unroll
    for (int nt = 0; nt < 4; ++nt)
#pragma unroll
      for (int k = 0; k < 4; ++k) s_frag[nt][k] = 0.0f;
#pragma unroll
    for (int kk = 0; kk < 64; kk += 32) {
      bf16x8 a = *(const bf16x8*)&Qs[(mrow + ln16) * 72 + kk + quad * 8];
#pragma unroll
      for (int nt = 0; nt < 4; ++nt) {
        bf16x8 bb = *(const bf16x8*)&Ks[(nt * 16 + ln16) * 72 + kk + quad * 8];
        s_frag[nt] = __builtin_amdgcn_mfma_f32_16x16x32_bf16(a, bb, s_frag[nt], 0, 0, 0);
      }
    }

#pragma unroll
    for (int reg = 0; reg < 4; ++reg) {
      float mv = s_frag[0][reg] * 0.125f;
#pragma unroll
      for (int nt = 0; nt < 4; ++nt) {
        s_frag[nt][reg] *= 0.125f;
        mv = fmaxf(mv, s_frag[nt][reg]);
      }
#pragma unroll
      for (int off = 1; off < 16; off <<= 1) mv = fmaxf(mv, __shfl_xor(mv, off));
      const float mn = fmaxf(m_i[reg], mv);
      const float al = __expf(m_i[reg] - mn);
      m_i[reg] = mn;
      float rs = 0.0f;
#pragma unroll
      for (int nt = 0; nt < 4; ++nt) {
        const float p = __expf(s_frag[nt][reg] - mn);
        s_frag[nt][reg] = p;
        rs += p;
      }
#pragma unroll
      for (int off = 1; off < 16; off <<= 1) rs += __shfl_xor(rs, off);
      l_i[reg] = l_i[reg] * al + rs;
#pragma unroll
      for (int nt = 0; nt < 4; ++nt) o_acc[nt][reg] *= al;
    }

#pragma unroll
    for (int nt = 0; nt < 4; ++nt)
#pragma unroll
      for (int reg = 0; reg < 4; ++reg)
        Ps[(mrow + quad * 4 + reg) * 72 + nt * 16 + ln16] = f2bf(s_frag[nt][reg]);

#pragma unroll
    for (int kk = 0; kk < 64; kk += 32) {
      bf16x8 a = *(const bf16x8*)&Ps[(mrow + ln16) * 72 + kk + quad * 8];
#pragma unroll
      for (int nt = 0; nt < 4; ++nt) {
        bf16x8 bb = *(const bf16x8*)&Vs[(nt * 16 + ln16) * 72 + kk + quad * 8];
        o_acc[nt] = __builtin_amdgcn_mfma_f32_16x16x32_bf16(a, bb, o_acc[nt], 0, 0, 0);
      }
    }
  }

#pragma unroll
  for (int reg = 0; reg < 4; ++reg) {
    const float inv = 1.0f / l_i[reg];
    const long t = t0 + mrow + quad * 4 + reg;
    const long base = ((long)b * SEQ + t) * 1024 + h * 64 + ln16;
#pragma unroll
    for (int nt = 0; nt < 4; ++nt)
      ob[base + nt * 16] = f2bf(o_acc[nt][reg] * inv);
  }
}

extern "C" void kernel_launch(void* const* d_in, const int* in_sizes, int n_in,
                              void* d_out, int out_size, void* d_ws, size_t ws_size,
                              hipStream_t stream) {
  const float* x       = (const float*)d_in[0];
  const float* xf      = (const float*)d_in[1];
  const float* Wqc     = (const float*)d_in[2];
  const float* gq      = (const float*)d_in[3];
  const float* bq      = (const float*)d_in[4];
  const float* Wq_rope = (const float*)d_in[5];   // rope before nope in dict order
  const float* Wq_nope = (const float*)d_in[6];
  const float* Wkvc    = (const float*)d_in[7];
  const float* gkv     = (const float*)d_in[8];
  const float* bkv     = (const float*)d_in[9];
  const float* Wk_nope = (const float*)d_in[10];
  const float* Wv      = (const float*)d_in[11];
  const float* Wkr     = (const float*)d_in[12];
  const float* Wo      = (const float*)d_in[13];
  const float* bo      = (const float*)d_in[14];
  float* out = (float*)d_out;

  const long R = 4096;
  float* ws = (float*)d_ws;
  float* ql_f  = ws;                       // 4096 x 256 f32
  float* kvl_f = ql_f + R * 256;           // 4096 x 204 f32
  float* scr_f = kvl_f + R * 204;          // 4096 x 512 f32 (kr_f -> qr_f -> v_bf)
  unsigned short* us = (unsigned short*)(scr_f + R * 512);
  unsigned short* x_bf   = us;             us += R * 1024;
  unsigned short* xf_bf  = us;             us += R * 1024;
  unsigned short* ql_bf  = us;             us += R * 256;
  unsigned short* kvl_bf = us;             us += R * 224;   // K-padded
  unsigned short* qn_bf  = us;             us += R * 512;
  unsigned short* qr_bf  = us;             us += R * 512;
  unsigned short* kn_bf  = us;             us += R * 512;
  unsigned short* kr_bf  = us;             us += R * 32;
  unsigned short* vT_bf  = us;             us += R * 1024;  // (B,H,64,S)
  unsigned short* o_bf   = us;             us += R * 1024;
  unsigned short* WqcT   = us;             us += 256 * 1024;
  unsigned short* WkvcT  = us;             us += 256 * 1024; // rows 204..255 zero
  unsigned short* WkrT   = us;             us += 128 * 1024; // rows 32..127 zero
  unsigned short* WqrT   = us;             us += 512 * 256;
  unsigned short* WqnT   = us;             us += 512 * 256;
  unsigned short* WknT   = us;             us += 512 * 224;  // cols 204..223 zero
  unsigned short* WvT    = us;             us += 1024 * 224;
  unsigned short* WoT    = us;             us += 1024 * 1024;
  unsigned short* v_bf   = (unsigned short*)scr_f;           // 4096 x 1024 bf16 (reuse)

  // 0) casts + weight transposes
  cast_kernel<<<4096, 256, 0, stream>>>(x,  x_bf,  4096 * 1024);
  cast_kernel<<<4096, 256, 0, stream>>>(xf, xf_bf, 4096 * 1024);
  transpose_cast_kernel<<<dim3(32, 8),  256, 0, stream>>>(Wqc,     WqcT,  1024,  256,  256, 1024);
  transpose_cast_kernel<<<dim3(32, 8),  256, 0, stream>>>(Wkvc,    WkvcT, 1024,  204,  256, 1024);
  transpose_cast_kernel<<<dim3(32, 4),  256, 0, stream>>>(Wkr,     WkrT,  1024,   32,  128, 1024);
  transpose_cast_kernel<<<dim3(8, 16),  256, 0, stream>>>(Wq_rope, WqrT,   256,  512,  512,  256);
  transpose_cast_kernel<<<dim3(8, 16),  256, 0, stream>>>(Wq_nope, WqnT,   256,  512,  512,  256);
  transpose_cast_kernel<<<dim3(7, 16),  256, 0, stream>>>(Wk_nope, WknT,   204,  512,  512,  224);
  transpose_cast_kernel<<<dim3(7, 32),  256, 0, stream>>>(Wv,      WvT,    204, 1024, 1024,  224);
  transpose_cast_kernel<<<dim3(32, 32), 256, 0, stream>>>(Wo,      WoT,   1024, 1024, 1024, 1024);

  // 1) ql = LN(x @ Wqc) -> bf16
  gemm_mfma<float, false><<<dim3(2, 32), 256, 0, stream>>>(x_bf, WqcT, nullptr, ql_f, 1024, 256);
  ln_kernel<<<4096, 256, 0, stream>>>(ql_f, gq, bq, ql_bf, 256, 256);
  // 2) kvl = LN(xf @ Wkvc) -> bf16, K-padded to 224
  gemm_mfma<float, false><<<dim3(2, 32), 256, 0, stream>>>(xf_bf, WkvcT, nullptr, kvl_f, 1024, 204);
  ln_kernel<<<4096, 256, 0, stream>>>(kvl_f, gkv, bkv, kvl_bf, 204, 224);
  // 3) kr = rope(xf @ Wkr)/H -> bf16
  gemm_mfma<float, false><<<dim3(1, 32), 256, 0, stream>>>(xf_bf, WkrT, nullptr, scr_f, 1024, 32);
  rope_kr_kernel<<<512, 256, 0, stream>>>(scr_f, kr_bf);
  // 4) qn = ql @ Wq_nope -> bf16
  gemm_mfma<unsigned short, false><<<dim3(4, 32), 256, 0, stream>>>(ql_bf, WqnT, nullptr, qn_bf, 256, 512);
  // 5) qr = rope(ql @ Wq_rope) -> bf16
  gemm_mfma<float, false><<<dim3(4, 32), 256, 0, stream>>>(ql_bf, WqrT, nullptr, scr_f, 256, 512);
  rope_q_kernel<<<4096, 512, 0, stream>>>(scr_f, qr_bf);
  // 6) kn = kvl @ Wk_nope -> bf16
  gemm_mfma<unsigned short, false><<<dim3(4, 32), 256, 0, stream>>>(kvl_bf, WknT, nullptr, kn_bf, 224, 512);
  // 7) v = kvl @ Wv -> bf16, then transpose to vT
  gemm_mfma<unsigned short, false><<<dim3(8, 32), 256, 0, stream>>>(kvl_bf, WvT, nullptr, v_bf, 224, 1024);
  transpose_v_kernel<<<dim3(32, 32), 256, 0, stream>>>(v_bf, vT_bf);
  // 8) attention -> o bf16
  attn_mfma_kernel<<<dim3(32, 32), 256, 0, stream>>>(qn_bf, qr_bf, kn_bf, kr_bf, vT_bf, o_bf);
  // 9) out = o @ Wo + bo (fp32 out)
  gemm_mfma<float, true><<<dim3(8, 32), 256, 0, stream>>>(o_bf, WoT, bo, out, 1024, 1024);
}